// Round 8
// baseline (1907.342 us; speedup 1.0000x reference)
//
#include <hip/hip_runtime.h>

// Problem constants (from reference)
constexpr int B_ = 16, T_ = 128, S_ = 128;
constexpr int ROWS = B_ * S_;        // 2048
constexpr int NSTEPS = T_ - 1;       // 127
constexpr int TPRED = 20;
constexpr int TOUT = NSTEPS - TPRED; // 107
constexpr int RPB = 32;              // owned rows per row-group (2 MFMA M-tiles)
constexpr int NPR = ROWS / RPB;      // 64 row-groups
constexpr int TB = 512;              // 8 waves
constexpr int NBLK = NPR * 4;        // 256 blocks = 64 row-groups x 4 col-quarters

// ws layout in 4-byte units (same offsets as previous rounds).
constexpr int OFF_HN = 0;                          // hn[2][2048][64] f16 -> 131072 dw
constexpr int OFF_HS = 131072;
constexpr int OFF_HD = 262144;                     // hd[2][2048][128] f16 -> 262144 dw
constexpr int OFF_CN = 524288;                     // cn[2][131072] f32 lane-order (dbuf)
constexpr int OFF_CS = 786432;
constexpr int OFF_CD = 1048576;                    // cd[64pr][4e][32r][32c] f32 (private)
constexpr int OFF_OUTS = 1310720;                  // outs[127][2048][2] f32 (atomicAdd)
constexpr int STATE_DWORDS = OFF_OUTS + NSTEPS * ROWS * 2;  // zero h+c+outs each call
// packed fp16 weight fragments (identical format to previous rounds)
constexpr int OFF_NPK = STATE_DWORDS;              // 16 nt * 7 tiles * 256 dw
constexpr int NPK_DW = 16 * 7 * 256;               // 28672
constexpr int OFF_SPK = OFF_NPK + NPK_DW;
constexpr int OFF_DPK = OFF_SPK + NPK_DW;          // 32 nt * 16 tiles * 256 dw
constexpr int DPK_DW = 32 * 16 * 256;              // 131072
constexpr int PACK_DWORDS = 2 * NPK_DW + DPK_DW;   // 188416

typedef _Float16 half8 __attribute__((ext_vector_type(8)));
typedef float float4v __attribute__((ext_vector_type(4)));

__device__ __forceinline__ float sigm(float x) { return 1.f / (1.f + __expf(-x)); }
__device__ __forceinline__ float tanh_(float x) { return 2.f / (1.f + __expf(-2.f * x)) - 1.f; }
__device__ __forceinline__ unsigned int pack2(float a, float b) {
    union { unsigned int u; _Float16 h[2]; } x;
    x.h[0] = (_Float16)a; x.h[1] = (_Float16)b; return x.u;
}

// ---- pack fp32 weights into MFMA B-fragment tiles (fp16), once per call ----
// B-frag for 16x16x32: lane l holds B[k=(l>>4)*8+j][n=l&15], j=0..7 -> tile = 512 f16 = 256 dw.
// n/s packs: per nt(16): [Wh kt0, Wh kt1, Wa kt0, Wa kt1, Wb kt0, Wb kt1, Xaug]
// d pack: per nt(32): [dWx kt0..3, dWh kt0..3, dWa kt0..3, dWb kt0..3]
__global__ __launch_bounds__(256) void pack_weights(
    const float* __restrict__ nWx, const float* __restrict__ nWh,
    const float* __restrict__ nWa, const float* __restrict__ nWb, const float* __restrict__ nb,
    const float* __restrict__ sWx, const float* __restrict__ sWh,
    const float* __restrict__ sWa, const float* __restrict__ sWb, const float* __restrict__ sb,
    const float* __restrict__ dWx, const float* __restrict__ dWh,
    const float* __restrict__ dWa, const float* __restrict__ dWb,
    unsigned int* __restrict__ wsu)
{
    int idx = blockIdx.x * 256 + threadIdx.x;
    if (idx >= PACK_DWORDS) return;
    if (idx < 2 * NPK_DW) {
        bool isS = idx >= NPK_DW;
        int dn = isS ? idx - NPK_DW : idx;
        int tile = dn >> 8;
        int e = (dn & 255) * 2;           // half index in tile (even)
        int lane = e >> 3, j0 = e & 7;
        int quad = lane >> 4;
        int nt = tile / 7, tt = tile % 7;
        int col = nt * 16 + (lane & 15);
        float v0, v1;
        if (tt < 6) {
            const float* W = isS ? ((tt < 2) ? sWh : (tt < 4) ? sWa : sWb)
                                 : ((tt < 2) ? nWh : (tt < 4) ? nWa : nWb);
            int k = (tt & 1) * 32 + quad * 8 + j0;
            v0 = W[k * 256 + col]; v1 = W[(k + 1) * 256 + col];
        } else {
            int kl = quad * 8 + j0;
            auto xv = [&](int k) -> float {
                if (!isS) { if (k < 3) return nWx[k * 256 + col]; if (k == 3) return nb[col]; return 0.f; }
                else      { if (k == 4) return sWx[col]; if (k == 5) return sb[col]; return 0.f; }
            };
            v0 = xv(kl); v1 = xv(kl + 1);
        }
        wsu[(isS ? OFF_SPK : OFF_NPK) + dn] = pack2(v0, v1);
    } else {
        int dd = idx - 2 * NPK_DW;
        int tile = dd >> 8;
        int e = (dd & 255) * 2;
        int lane = e >> 3, j0 = e & 7;
        int quad = lane >> 4;
        int nt = tile >> 4, tt = tile & 15;
        const float* W = (tt < 4) ? dWx : (tt < 8) ? dWh : (tt < 12) ? dWa : dWb;
        int k = (tt & 3) * 32 + quad * 8 + j0;
        int col = nt * 16 + (lane & 15);
        wsu[OFF_DPK + dd] = pack2(W[k * 512 + col], W[(k + 1) * 512 + col]);
    }
}

__global__ __launch_bounds__(TB) void step_kernel(
    int t,
    const float* __restrict__ input,
    const float* __restrict__ db,
    const float* __restrict__ onW, const float* __restrict__ osW,
    float* __restrict__ ws)
{
    const int cur = t & 1, nxt = cur ^ 1;
    _Float16* hnB = (_Float16*)((unsigned int*)ws + OFF_HN);
    _Float16* hsB = (_Float16*)((unsigned int*)ws + OFF_HS);
    _Float16* hdB = (_Float16*)((unsigned int*)ws + OFF_HD);
    const _Float16* hnC = hnB + cur * ROWS * 64;
    const _Float16* hsC = hsB + cur * ROWS * 64;
    const _Float16* hdC = hdB + cur * ROWS * 128;
    _Float16* hnN = hnB + nxt * ROWS * 64;
    _Float16* hsN = hsB + nxt * ROWS * 64;
    _Float16* hdN = hdB + nxt * ROWS * 128;
    float* cnB = ws + OFF_CN;
    float* csB = ws + OFF_CS;
    float* cd  = ws + OFF_CD;
    float* outs = ws + OFF_OUTS;

    const int tid = threadIdx.x;
    const int wave = tid >> 6, lane = tid & 63;
    const int quad = lane >> 4, l15 = lane & 15;
    const int blk = blockIdx.x;
    const int pr = blk >> 2;          // row-group (32 rows)
    const int e = blk & 3;            // column quarter of d-cell / heads
    const int r0 = pr * RPB;
    const int b = pr >> 2;
    const int s0 = (pr & 3) * 32;
    const bool leftOK = ((pr & 3) != 0);
    const bool rightOK = ((pr & 3) != 3);

    // LDS (~66 KB): staged rows 0..33 = global rows r0-1 .. r0+32
    __shared__ __align__(16) _Float16 sh_hn[34 * 72];
    __shared__ __align__(16) _Float16 sh_hs[34 * 72];
    __shared__ __align__(16) _Float16 sh_hd[34 * 136];
    __shared__ __align__(16) _Float16 sh_xa[32 * 40];   // x_aug per owned row
    __shared__ __align__(16) _Float16 sh_dec[32 * 136]; // dec_in fp16 (phase-B A operand)
    __shared__ float sh_hdnew[32 * 32];                 // own 32-col quarter (heads)
    __shared__ float sh_gd[2 * 4 * 2 * 2 * 256];        // [kp][g][ct][tile][lane*4+reg] 32KB

    // ---- phase-A B-fragments: hoist loads BEFORE staging (overlap stream w/ staging) ----
    const int ctA = wave & 3;
    const bool isS = (wave >= 4);
    const _Float16* pk = (const _Float16*)((const unsigned int*)ws + (isS ? OFF_SPK : OFF_NPK));
    half8 Bf[4][7];
#pragma unroll
    for (int g = 0; g < 4; ++g) {
        const _Float16* bb = pk + (size_t)(4 * g + ctA) * 7 * 512 + lane * 8;
#pragma unroll
        for (int j = 0; j < 7; ++j) Bf[g][j] = *(const half8*)(bb + j * 512);
    }

    // ---- stage h (+/-1 halo) as dwords into padded LDS ----
    for (int i = tid; i < 4352; i += TB) {
        if (i < 1088) {
            int row = i >> 5, p = i & 31;
            int grow = r0 + row - 1;
            bool v = (row == 0) ? leftOK : ((row == 33) ? rightOK : true);
            unsigned int val = v ? ((const unsigned int*)hnC)[grow * 32 + p] : 0u;
            *(unsigned int*)(sh_hn + row * 72 + 2 * p) = val;
        } else if (i < 2176) {
            int j = i - 1088;
            int row = j >> 5, p = j & 31;
            int grow = r0 + row - 1;
            bool v = (row == 0) ? leftOK : ((row == 33) ? rightOK : true);
            unsigned int val = v ? ((const unsigned int*)hsC)[grow * 32 + p] : 0u;
            *(unsigned int*)(sh_hs + row * 72 + 2 * p) = val;
        } else {
            int j = i - 2176;
            int row = j >> 6, p = j & 63;
            int grow = r0 + row - 1;
            bool v = (row == 0) ? leftOK : ((row == 33) ? rightOK : true);
            unsigned int val = v ? ((const unsigned int*)hdC)[grow * 64 + p] : 0u;
            *(unsigned int*)(sh_hd + row * 136 + 2 * p) = val;
        }
    }
    // x_aug: zero dwords 3..19 of each 20-dword row, then fill 0..2 (disjoint threads)
    for (int i = tid; i < 544; i += TB) {
        int r = i / 17, d = 3 + (i % 17);
        ((unsigned int*)sh_xa)[r * 20 + d] = 0u;
    }
    if (tid < 32) {
        const float* xp = input + ((size_t)(b * T_ + t) * S_ + (s0 + tid)) * 4;
        unsigned int* row = (unsigned int*)sh_xa + tid * 20;
        row[0] = pack2(xp[0], xp[1]);
        row[1] = pack2(xp[2], 1.f);
        row[2] = pack2(xp[3], 1.f);
    }
    __syncthreads();

    // ---- phase A: n-cell (waves 0-3) / s-cell (waves 4-7), 2 row-tiles per wave ----
    {
        const _Float16* hb = isS ? sh_hs : sh_hn;
        const int kcol = 16 * ctA + l15;
#pragma unroll
        for (int tile = 0; tile < 2; ++tile) {
            const int rbase = tile * 16 + l15;
            half8 ah0 = *(const half8*)(hb + (rbase + 1) * 72 + quad * 8);
            half8 ah1 = *(const half8*)(hb + (rbase + 1) * 72 + 32 + quad * 8);
            half8 aa0 = *(const half8*)(hb + (rbase + 2) * 72 + quad * 8);
            half8 aa1 = *(const half8*)(hb + (rbase + 2) * 72 + 32 + quad * 8);
            half8 ab0 = *(const half8*)(hb + (rbase) * 72 + quad * 8);
            half8 ab1 = *(const half8*)(hb + (rbase) * 72 + 32 + quad * 8);
            half8 ax  = *(const half8*)(sh_xa + rbase * 40 + quad * 8);
            float4v acc[4];
#pragma unroll
            for (int g = 0; g < 4; ++g) acc[g] = (float4v){0.f, 0.f, 0.f, 0.f};
#pragma unroll
            for (int g = 0; g < 4; ++g) {
                acc[g] = __builtin_amdgcn_mfma_f32_16x16x32_f16(ah0, Bf[g][0], acc[g], 0, 0, 0);
                acc[g] = __builtin_amdgcn_mfma_f32_16x16x32_f16(ah1, Bf[g][1], acc[g], 0, 0, 0);
                acc[g] = __builtin_amdgcn_mfma_f32_16x16x32_f16(aa0, Bf[g][2], acc[g], 0, 0, 0);
                acc[g] = __builtin_amdgcn_mfma_f32_16x16x32_f16(aa1, Bf[g][3], acc[g], 0, 0, 0);
                acc[g] = __builtin_amdgcn_mfma_f32_16x16x32_f16(ab0, Bf[g][4], acc[g], 0, 0, 0);
                acc[g] = __builtin_amdgcn_mfma_f32_16x16x32_f16(ab1, Bf[g][5], acc[g], 0, 0, 0);
                acc[g] = __builtin_amdgcn_mfma_f32_16x16x32_f16(ax,  Bf[g][6], acc[g], 0, 0, 0);
            }
            // epilogue: c dbuf lane-order; e0 persists n/s state
            float* cB = isS ? csB : cnB;
            size_t cIdx = ((size_t)((pr * 2 + tile) * 4 + ctA) * 64 + lane) * 4;
            float4v cold = *(const float4v*)(cB + (size_t)cur * 131072 + cIdx);
            float4v cnew;
            _Float16* hN = isS ? hsN : hnN;
#pragma unroll
            for (int r = 0; r < 4; ++r) {
                float c2 = sigm(acc[1][r]) * cold[r] + sigm(acc[0][r]) * tanh_(acc[2][r]);
                float h2 = sigm(acc[3][r]) * tanh_(c2);
                cnew[r] = c2;
                int orow = tile * 16 + quad * 4 + r;
                sh_dec[orow * 136 + (isS ? 64 : 0) + kcol] = (_Float16)h2;
                if (e == 0) hN[(size_t)(r0 + orow) * 64 + kcol] = (_Float16)h2;
            }
            if (e == 0) *(float4v*)(cB + (size_t)nxt * 131072 + cIdx) = cnew;
        }
    }

    // ---- phase-B B-fragments: prefetch before the dec-ready barrier ----
    const int ct2 = wave & 1;
    const int gp = (wave >> 1) & 1;   // gate pair: {0,1} or {2,3}
    const int kp = wave >> 2;         // K half: kt 0-7 or 8-15
    const _Float16* pd = (const _Float16*)((const unsigned int*)ws + OFF_DPK);
    half8 Df[2][8];
#pragma unroll
    for (int gg = 0; gg < 2; ++gg) {
        int g = 2 * gp + gg;
        int nt = g * 8 + e * 2 + ct2;
        const _Float16* bb = pd + ((size_t)nt * 16 + kp * 8) * 512 + lane * 8;
#pragma unroll
        for (int j = 0; j < 8; ++j) Df[gg][j] = *(const half8*)(bb + j * 512);
    }
    __syncthreads();

    // ---- phase B: d-cell MFMA burst (register-resident weights) ----
    {
        float4v accB[2][2];
#pragma unroll
        for (int gg = 0; gg < 2; ++gg)
#pragma unroll
            for (int tl = 0; tl < 2; ++tl) accB[gg][tl] = (float4v){0.f, 0.f, 0.f, 0.f};
#pragma unroll
        for (int tl = 0; tl < 2; ++tl) {
            const int rbase = tl * 16 + l15;
#pragma unroll
            for (int j = 0; j < 8; ++j) {
                int kt = kp * 8 + j;
                int w = kt >> 2, kw = kt & 3;   // w: 0 dec, 1 hd self, 2 hd+1, 3 hd-1
                const _Float16* src;
                if (w == 0)      src = sh_dec + rbase * 136 + kw * 32 + quad * 8;
                else if (w == 1) src = sh_hd + (rbase + 1) * 136 + kw * 32 + quad * 8;
                else if (w == 2) src = sh_hd + (rbase + 2) * 136 + kw * 32 + quad * 8;
                else             src = sh_hd + (rbase) * 136 + kw * 32 + quad * 8;
                half8 a = *(const half8*)src;
                accB[0][tl] = __builtin_amdgcn_mfma_f32_16x16x32_f16(a, Df[0][j], accB[0][tl], 0, 0, 0);
                accB[1][tl] = __builtin_amdgcn_mfma_f32_16x16x32_f16(a, Df[1][j], accB[1][tl], 0, 0, 0);
            }
        }
#pragma unroll
        for (int gg = 0; gg < 2; ++gg)
#pragma unroll
            for (int tl = 0; tl < 2; ++tl) {
                int slot = (((kp * 4 + (2 * gp + gg)) * 2 + ct2) * 2 + tl);
                *(float4v*)&sh_gd[slot * 256 + lane * 4] = accB[gg][tl];
            }
    }
    __syncthreads();

    // ---- epilogue B: gate combine over own 32x32; c private; persist hd quarter ----
#pragma unroll
    for (int it = tid; it < 1024; it += TB) {
        int row = it >> 5, col = it & 31;
        int tl = row >> 4, rl = row & 15;
        int q = rl >> 2, rg = rl & 3;
        int ctl = col >> 4, l = col & 15;
        int li = (q * 16 + l) * 4 + rg;
        float gv[4];
#pragma unroll
        for (int g = 0; g < 4; ++g) {
            int s0i = (((0 * 4 + g) * 2 + ctl) * 2 + tl) * 256 + li;
            int s1i = (((1 * 4 + g) * 2 + ctl) * 2 + tl) * 256 + li;
            gv[g] = sh_gd[s0i] + sh_gd[s1i];
        }
        int kd = 32 * e + col;
        float bi = db[kd], bf = db[128 + kd], bu = db[256 + kd], bo = db[384 + kd];
        size_t ci = ((size_t)(pr * 4 + e) * 1024) + row * 32 + col;
        float cold = cd[ci];
        float c2 = sigm(gv[1] + bf) * cold + sigm(gv[0] + bi) * tanh_(gv[2] + bu);
        float h2 = sigm(gv[3] + bo) * tanh_(c2);
        cd[ci] = c2;
        hdN[(size_t)(r0 + row) * 128 + kd] = (_Float16)h2;
        sh_hdnew[row * 32 + col] = h2;
    }
    __syncthreads();

    // ---- output heads: partial over own 32 cols; atomicAdd into zeroed outs ----
    {
        int p = tid >> 3, l8 = tid & 7;    // 64 groups = 32 rows x 2 heads
        int row = p >> 1, head = p & 1;
        const float* W = (head ? osW : onW) + 32 * e;
        float partial = 0.f;
#pragma unroll
        for (int k = 0; k < 32; k += 8) partial += sh_hdnew[row * 32 + k + l8] * W[k + l8];
#pragma unroll
        for (int off = 4; off; off >>= 1) partial += __shfl_down(partial, off, 8);
        if (l8 == 0) atomicAdd(&outs[((size_t)t * ROWS + (r0 + row)) * 2 + head], partial);
    }
}

// Assemble data outputs for t in [20,126]; head biases applied here.
__global__ __launch_bounds__(256) void assemble_kernel(
    const float* __restrict__ input, const float* __restrict__ ws,
    const float* __restrict__ onb, const float* __restrict__ osb,
    float* __restrict__ out)
{
    const float* outs = ws + OFF_OUTS;
    int idx = blockIdx.x * 256 + threadIdx.x;  // (b, tt, s)
    if (idx >= B_ * TOUT * S_) return;
    int s = idx & 127;
    int tmp = idx >> 7;
    int tt = tmp % TOUT;
    int b = tmp / TOUT;
    int t = tt + TPRED;
    int row = b * S_ + s;
    float ob0 = onb[0], ob1 = osb[0];
    float o0 = outs[((size_t)t * ROWS + row) * 2 + 0] + ob0;
    float o1 = outs[((size_t)t * ROWS + row) * 2 + 1] + ob1;
    float inflow = (s == 0) ? input[(((size_t)b * T_ + (t + 1)) * S_ + 0) * 4 + 1]
                            : (outs[((size_t)t * ROWS + row - 1) * 2 + 0] + ob0);
    float numc = input[(((size_t)b * T_ + t) * S_ + s) * 4 + 2] + inflow - o0;
    float spd = (s == 0) ? input[(((size_t)b * T_ + (t + 1)) * S_ + 0) * 4 + 3] : o1;
    float4 v = make_float4(o0, inflow, numc, spd);
    reinterpret_cast<float4*>(out)[idx] = v;
}

extern "C" void kernel_launch(void* const* d_in, const int* in_sizes, int n_in,
                              void* d_out, int out_size, void* d_ws, size_t ws_size,
                              hipStream_t stream) {
    const float* input = (const float*)d_in[0];
    const float* nWx = (const float*)d_in[1];
    const float* nWh = (const float*)d_in[2];
    const float* nWa = (const float*)d_in[3];
    const float* nWb = (const float*)d_in[4];
    const float* nb  = (const float*)d_in[5];
    const float* sWx = (const float*)d_in[6];
    const float* sWh = (const float*)d_in[7];
    const float* sWa = (const float*)d_in[8];
    const float* sWb = (const float*)d_in[9];
    const float* sb  = (const float*)d_in[10];
    const float* dWx = (const float*)d_in[11];
    const float* dWh = (const float*)d_in[12];
    const float* dWa = (const float*)d_in[13];
    const float* dWb = (const float*)d_in[14];
    const float* db  = (const float*)d_in[15];
    const float* onW = (const float*)d_in[16];
    const float* onb = (const float*)d_in[17];
    const float* osW = (const float*)d_in[18];
    const float* osb = (const float*)d_in[19];

    float* ws = (float*)d_ws;

    // zero h, c, and outs (outs is atomicAdd-accumulated); ws poisoned 0xAA pre-call
    hipMemsetAsync(ws, 0, (size_t)STATE_DWORDS * 4, stream);

    // pack weights into MFMA B-fragment tiles (once per call)
    pack_weights<<<dim3((PACK_DWORDS + 255) / 256), dim3(256), 0, stream>>>(
        nWx, nWh, nWa, nWb, nb, sWx, sWh, sWa, sWb, sb,
        dWx, dWh, dWa, dWb, (unsigned int*)ws);

    for (int t = 0; t < NSTEPS; ++t) {
        step_kernel<<<dim3(NBLK), dim3(TB), 0, stream>>>(
            t, input, db, onW, osW, ws);
    }

    int nout = B_ * TOUT * S_;
    assemble_kernel<<<dim3((nout + 255) / 256), dim3(256), 0, stream>>>(
        input, ws, onb, osb, (float*)d_out);
}